// Round 2
// baseline (60.059 us; speedup 1.0000x reference)
//
#include <hip/hip_runtime.h>
#include <hip/hip_bf16.h>

// N = 16384 rows, D_TS = 1022 ts cols, D = 1024 total cols, C = 2, GAMMA = 0.1
// Reference:
//   x = concat(ts, meta0, meta1)                 [N, 1024]
//   S[d] = sum_i x[i,d]; Q[d] = sum_i x[i,d]^2
//   pairwise_sq[i,d] = N*x^2 - 2*x*S[d] + Q[d]
//   out = exp(-GAMMA*pairwise_sq) @ w.T + b      [N, 2] fp32
//
// Workspace: colS [1024], colQ [1024] (zeroed via hipMemsetAsync each call).
// Atomic-float finalization is deterministic-safe here: pairwise_sq >= ~1600
// for this data, so exp() underflows to exactly 0.0f and out == b bitwise
// regardless of last-ulp ordering in the column sums (round-1 absmax was 0.0).

#define NROWS   16384
#define DTS     1022
#define DTOT    1024
#define NCHUNK  512                 // row chunks; 1024 blocks total (4/CU)
#define RPC     (NROWS / NCHUNK)    // 32 rows per chunk
#define GAMMA_F 0.1f

// ---------------------------------------------------------------------------
// K1: column sums/sq-sums with atomic finalization.
// grid = (2 col-tiles, NCHUNK) = 1024 blocks, 256 thr. Thread owns 2 adjacent
// columns (float2 loads, 8B-aligned since row stride 1022 floats) x 32 rows,
// then 4 atomicAdds. 512 contenders per address -> ~1 us.
// ---------------------------------------------------------------------------
__global__ __launch_bounds__(256) void colsum_atomic(
    const float* __restrict__ ts, const float* __restrict__ m0,
    const float* __restrict__ m1, float* __restrict__ colS,
    float* __restrict__ colQ) {
  const int tile  = blockIdx.x;                    // 0..1
  const int chunk = blockIdx.y;                    // 0..NCHUNK-1
  const int d     = tile * 512 + threadIdx.x * 2;  // even, 0..1022
  const int r0    = chunk * RPC;

  float s0 = 0.f, s1 = 0.f, q0 = 0.f, q1 = 0.f;
  if (d < DTS) {
    const float* p = ts + (size_t)r0 * DTS + d;
#pragma unroll 8
    for (int r = 0; r < RPC; ++r) {
      float2 v = *reinterpret_cast<const float2*>(p);
      s0 += v.x; s1 += v.y;
      q0 += v.x * v.x; q1 += v.y * v.y;
      p += DTS;
    }
  } else {  // d == 1022: metadata columns
#pragma unroll 8
    for (int r = 0; r < RPC; ++r) {
      float a = m0[r0 + r], b = m1[r0 + r];
      s0 += a; s1 += b;
      q0 += a * a; q1 += b * b;
    }
  }
  atomicAdd(&colS[d], s0);
  atomicAdd(&colS[d + 1], s1);
  atomicAdd(&colQ[d], q0);
  atomicAdd(&colQ[d + 1], q1);
}

// ---------------------------------------------------------------------------
// K2: fused feat + GEMV. grid = 1024 blocks x 256 thr (4 waves). Each wave
// handles 4 consecutive rows (amortizes the 16 KB LDS constant staging 4x).
// Per row: 8 float2 loads over 1024 cols, exp + 2-way dot, butterfly reduce.
// ---------------------------------------------------------------------------
__global__ __launch_bounds__(256) void svm_logits(
    const float* __restrict__ ts, const float* __restrict__ m0,
    const float* __restrict__ m1, const float* __restrict__ w,
    const float* __restrict__ b, const float* __restrict__ colS,
    const float* __restrict__ colQ, float* __restrict__ out) {
  __shared__ float sW0[DTOT], sW1[DTOT], sC1[DTOT], sC0[DTOT];
  const int tid = threadIdx.x;
  const float b0 = b[0], b1 = b[1];  // uniform -> scalar loads
  for (int k = tid; k < DTOT; k += 256) {
    sW0[k] = w[k];
    sW1[k] = w[DTOT + k];
    sC1[k] = 2.0f * GAMMA_F * colS[k];
    sC0[k] = -GAMMA_F * colQ[k];
  }
  __syncthreads();

  const int wave = tid >> 6, lane = tid & 63;
  const int gw   = blockIdx.x * 4 + wave;      // 0..4095
  const float c2 = -GAMMA_F * (float)NROWS;    // -gamma*N

#pragma unroll
  for (int rr = 0; rr < 4; ++rr) {
    const int i = gw * 4 + rr;                 // row, < 16384
    const float* row = ts + (size_t)i * DTS;
    float acc0 = 0.f, acc1 = 0.f;
#pragma unroll
    for (int k = 0; k < 8; ++k) {
      const int d = k * 128 + lane * 2;        // even, 0..1022
      float x0, x1;
      if (d < DTS) {
        float2 v = *reinterpret_cast<const float2*>(row + d);
        x0 = v.x; x1 = v.y;
      } else {                                 // d == 1022 -> meta columns
        x0 = m0[i]; x1 = m1[i];
      }
      const float p0 = (c2 * x0 + sC1[d]) * x0 + sC0[d];
      const float p1 = (c2 * x1 + sC1[d + 1]) * x1 + sC0[d + 1];
      const float f0 = __expf(p0);
      const float f1 = __expf(p1);
      acc0 += f0 * sW0[d] + f1 * sW0[d + 1];
      acc1 += f0 * sW1[d] + f1 * sW1[d + 1];
    }
#pragma unroll
    for (int off = 32; off; off >>= 1) {
      acc0 += __shfl_down(acc0, off);
      acc1 += __shfl_down(acc1, off);
    }
    if (lane == 0) {
      out[i * 2 + 0] = acc0 + b0;
      out[i * 2 + 1] = acc1 + b1;
    }
  }
}

extern "C" void kernel_launch(void* const* d_in, const int* in_sizes, int n_in,
                              void* d_out, int out_size, void* d_ws,
                              size_t ws_size, hipStream_t stream) {
  const float* ts = (const float*)d_in[0];   // [16384, 1022]
  const float* m0 = (const float*)d_in[1];   // [16384]
  const float* m1 = (const float*)d_in[2];   // [16384]
  const float* w  = (const float*)d_in[3];   // [2, 1024]
  const float* b  = (const float*)d_in[4];   // [2]
  float* out = (float*)d_out;                // [16384, 2]

  float* colS = (float*)d_ws;                // [1024]
  float* colQ = colS + DTOT;                 // [1024]

  hipMemsetAsync(d_ws, 0, 2 * DTOT * sizeof(float), stream);
  colsum_atomic<<<dim3(2, NCHUNK), 256, 0, stream>>>(ts, m0, m1, colS, colQ);
  svm_logits<<<dim3(1024), 256, 0, stream>>>(ts, m0, m1, w, b, colS, colQ,
                                             out);
}

// Round 3
// 37.329 us; speedup vs baseline: 1.6089x; 1.6089x over previous
//
#include <hip/hip_runtime.h>
#include <hip/hip_bf16.h>

// N = 16384 rows, D_TS = 1022 ts cols, D = 1024 total cols, C = 2, GAMMA = 0.1
// Reference:
//   x = concat(ts, meta0, meta1)                 [N, 1024]
//   S[d] = sum_i x[i,d]; Q[d] = sum_i x[i,d]^2
//   pairwise_sq[i,d] = N*x^2 - 2*x*S[d] + Q[d]
//   out = exp(-GAMMA*pairwise_sq) @ w.T + b      [N, 2] fp32
//
// Round-2 lesson: contended fp32 atomics onto 8 KB (512 contenders/address,
// cross-XCD) cost 44 us alone. Back to deterministic 2-level reduce with a
// PARALLEL second level (round-1's K2 used only 4 blocks).
//
// Workspace: psum [512][1024], psq [512][1024], colS [1024], colQ [1024]
// (~4.01 MB; ws is ~268 MB).

#define NROWS   16384
#define DTS     1022
#define DTOT    1024
#define NCHUNK  512                 // row chunks; K1 grid = 1024 blocks (4/CU)
#define RPC     (NROWS / NCHUNK)    // 32 rows per chunk
#define GAMMA_F 0.1f

// ---------------------------------------------------------------------------
// K1: per-chunk column sums / sq-sums. grid = (2 col-tiles, NCHUNK), 256 thr.
// Thread owns 2 adjacent columns (float2, 8B-aligned since row stride is 1022
// floats) x 32 rows; writes one float2 per array. No atomics.
// ---------------------------------------------------------------------------
__global__ __launch_bounds__(256) void colsum_partial(
    const float* __restrict__ ts, const float* __restrict__ m0,
    const float* __restrict__ m1, float* __restrict__ psum,
    float* __restrict__ psq) {
  const int tile  = blockIdx.x;                    // 0..1
  const int chunk = blockIdx.y;                    // 0..NCHUNK-1
  const int d     = tile * 512 + threadIdx.x * 2;  // even, 0..1022
  const int r0    = chunk * RPC;

  float s0 = 0.f, s1 = 0.f, q0 = 0.f, q1 = 0.f;
  if (d < DTS) {
    const float* p = ts + (size_t)r0 * DTS + d;
#pragma unroll 8
    for (int r = 0; r < RPC; ++r) {
      float2 v = *reinterpret_cast<const float2*>(p);
      s0 += v.x; s1 += v.y;
      q0 += v.x * v.x; q1 += v.y * v.y;
      p += DTS;
    }
  } else {  // d == 1022: metadata columns
#pragma unroll 8
    for (int r = 0; r < RPC; ++r) {
      float a = m0[r0 + r], b = m1[r0 + r];
      s0 += a; s1 += b;
      q0 += a * a; q1 += b * b;
    }
  }
  const int o = chunk * DTOT + d;
  *reinterpret_cast<float2*>(psum + o) = make_float2(s0, s1);
  *reinterpret_cast<float2*>(psq + o)  = make_float2(q0, q1);
}

// ---------------------------------------------------------------------------
// K2: parallel chunk reduction. grid = 16 blocks x 256 thr. Block owns 64
// consecutive columns; lane <-> column (coalesced 256 B per wave-load), wave
// w strides chunks w, w+4, ... (128 each); LDS combine across the 4 waves.
// ---------------------------------------------------------------------------
__global__ __launch_bounds__(256) void colsum_final(
    const float* __restrict__ psum, const float* __restrict__ psq,
    float* __restrict__ colS, float* __restrict__ colQ) {
  const int wave = threadIdx.x >> 6, lane = threadIdx.x & 63;
  const int c = blockIdx.x * 64 + lane;  // 0..1023
  float s = 0.f, q = 0.f;
#pragma unroll 8
  for (int ch = wave; ch < NCHUNK; ch += 4) {
    s += psum[ch * DTOT + c];
    q += psq[ch * DTOT + c];
  }
  __shared__ float ls[4][64], lq[4][64];
  ls[wave][lane] = s;
  lq[wave][lane] = q;
  __syncthreads();
  if (wave == 0) {
    colS[c] = ls[0][lane] + ls[1][lane] + ls[2][lane] + ls[3][lane];
    colQ[c] = lq[0][lane] + lq[1][lane] + lq[2][lane] + lq[3][lane];
  }
}

// ---------------------------------------------------------------------------
// K3: fused feat + GEMV. grid = 512 blocks x 256 thr (4 waves); each wave
// handles 8 consecutive rows (halves the per-block 16 KB constant staging
// traffic vs 1024 blocks). Per row: 8 float2 loads over 1024 cols, exp +
// 2-way dot, 64-lane butterfly reduce, lane 0 writes 2 floats.
// ---------------------------------------------------------------------------
__global__ __launch_bounds__(256) void svm_logits(
    const float* __restrict__ ts, const float* __restrict__ m0,
    const float* __restrict__ m1, const float* __restrict__ w,
    const float* __restrict__ b, const float* __restrict__ colS,
    const float* __restrict__ colQ, float* __restrict__ out) {
  __shared__ float sW0[DTOT], sW1[DTOT], sC1[DTOT], sC0[DTOT];
  const int tid = threadIdx.x;
  const float b0 = b[0], b1 = b[1];  // uniform -> scalar loads
  for (int k = tid; k < DTOT; k += 256) {
    sW0[k] = w[k];
    sW1[k] = w[DTOT + k];
    sC1[k] = 2.0f * GAMMA_F * colS[k];
    sC0[k] = -GAMMA_F * colQ[k];
  }
  __syncthreads();

  const int wave = tid >> 6, lane = tid & 63;
  const int gw   = blockIdx.x * 4 + wave;      // 0..2047
  const float c2 = -GAMMA_F * (float)NROWS;    // -gamma*N

#pragma unroll
  for (int rr = 0; rr < 8; ++rr) {
    const int i = gw * 8 + rr;                 // row, < 16384
    const float* row = ts + (size_t)i * DTS;
    float acc0 = 0.f, acc1 = 0.f;
#pragma unroll
    for (int k = 0; k < 8; ++k) {
      const int d = k * 128 + lane * 2;        // even, 0..1022
      float x0, x1;
      if (d < DTS) {
        float2 v = *reinterpret_cast<const float2*>(row + d);
        x0 = v.x; x1 = v.y;
      } else {                                 // d == 1022 -> meta columns
        x0 = m0[i]; x1 = m1[i];
      }
      const float p0 = (c2 * x0 + sC1[d]) * x0 + sC0[d];
      const float p1 = (c2 * x1 + sC1[d + 1]) * x1 + sC0[d + 1];
      const float f0 = __expf(p0);
      const float f1 = __expf(p1);
      acc0 += f0 * sW0[d] + f1 * sW0[d + 1];
      acc1 += f0 * sW1[d] + f1 * sW1[d + 1];
    }
#pragma unroll
    for (int off = 32; off; off >>= 1) {
      acc0 += __shfl_down(acc0, off);
      acc1 += __shfl_down(acc1, off);
    }
    if (lane == 0) {
      out[i * 2 + 0] = acc0 + b0;
      out[i * 2 + 1] = acc1 + b1;
    }
  }
}

extern "C" void kernel_launch(void* const* d_in, const int* in_sizes, int n_in,
                              void* d_out, int out_size, void* d_ws,
                              size_t ws_size, hipStream_t stream) {
  const float* ts = (const float*)d_in[0];   // [16384, 1022]
  const float* m0 = (const float*)d_in[1];   // [16384]
  const float* m1 = (const float*)d_in[2];   // [16384]
  const float* w  = (const float*)d_in[3];   // [2, 1024]
  const float* b  = (const float*)d_in[4];   // [2]
  float* out = (float*)d_out;                // [16384, 2]

  float* psum = (float*)d_ws;                // [NCHUNK][1024]
  float* psq  = psum + NCHUNK * DTOT;        // [NCHUNK][1024]
  float* colS = psq + NCHUNK * DTOT;         // [1024]
  float* colQ = colS + DTOT;                 // [1024]

  colsum_partial<<<dim3(2, NCHUNK), 256, 0, stream>>>(ts, m0, m1, psum, psq);
  colsum_final<<<dim3(16), 256, 0, stream>>>(psum, psq, colS, colQ);
  svm_logits<<<dim3(512), 256, 0, stream>>>(ts, m0, m1, w, b, colS, colQ,
                                            out);
}

// Round 4
// 34.029 us; speedup vs baseline: 1.7649x; 1.0970x over previous
//
#include <hip/hip_runtime.h>
#include <hip/hip_bf16.h>

// N = 16384 rows, D_TS = 1022 ts cols, D = 1024 total cols, C = 2, GAMMA = 0.1
// Reference:
//   x = concat(ts, meta0, meta1)                 [N, 1024]
//   S[d] = sum_i x[i,d]; Q[d] = sum_i x[i,d]^2
//   pairwise_sq[i,d] = N*x^2 - 2*x*S[d] + Q[d]
//   out = exp(-GAMMA*pairwise_sq) @ w.T + b      [N, 2] fp32
//
// Round-2 lesson: contended fp32 atomics = 44 us. Round-3 lesson (analytic):
// K3's 8x ds_read_b32 per 2 elements ~= 10 us of LDS-pipe time; each lane's
// 16 columns are FIXED across rows -> keep all constants in registers.
//
// Workspace: psum [512][1024], psq [512][1024], colS [1024], colQ [1024].

#define NROWS   16384
#define DTS     1022
#define DTOT    1024
#define NCHUNK  512                 // row chunks; K1 grid = 1024 blocks (4/CU)
#define RPC     (NROWS / NCHUNK)    // 32 rows per chunk
#define GAMMA_F 0.1f

// ---------------------------------------------------------------------------
// K1: per-chunk column sums / sq-sums. grid = (2 col-tiles, NCHUNK), 256 thr.
// Thread owns 2 adjacent columns (float2, 8B-aligned since row stride is 1022
// floats) x 32 rows; writes one float2 per array. No atomics.
// ---------------------------------------------------------------------------
__global__ __launch_bounds__(256) void colsum_partial(
    const float* __restrict__ ts, const float* __restrict__ m0,
    const float* __restrict__ m1, float* __restrict__ psum,
    float* __restrict__ psq) {
  const int tile  = blockIdx.x;                    // 0..1
  const int chunk = blockIdx.y;                    // 0..NCHUNK-1
  const int d     = tile * 512 + threadIdx.x * 2;  // even, 0..1022
  const int r0    = chunk * RPC;

  float s0 = 0.f, s1 = 0.f, q0 = 0.f, q1 = 0.f;
  if (d < DTS) {
    const float* p = ts + (size_t)r0 * DTS + d;
#pragma unroll 8
    for (int r = 0; r < RPC; ++r) {
      float2 v = *reinterpret_cast<const float2*>(p);
      s0 += v.x; s1 += v.y;
      q0 += v.x * v.x; q1 += v.y * v.y;
      p += DTS;
    }
  } else {  // d == 1022: metadata columns
#pragma unroll 8
    for (int r = 0; r < RPC; ++r) {
      float a = m0[r0 + r], b = m1[r0 + r];
      s0 += a; s1 += b;
      q0 += a * a; q1 += b * b;
    }
  }
  const int o = chunk * DTOT + d;
  *reinterpret_cast<float2*>(psum + o) = make_float2(s0, s1);
  *reinterpret_cast<float2*>(psq + o)  = make_float2(q0, q1);
}

// ---------------------------------------------------------------------------
// K2: parallel chunk reduction. grid = 16 blocks x 1024 thr (16 waves).
// Block owns 64 consecutive columns; lane <-> column (coalesced 256 B/wave),
// wave w strides chunks w, w+16, ... (32 each); LDS combine across 16 waves.
// ---------------------------------------------------------------------------
__global__ __launch_bounds__(1024) void colsum_final(
    const float* __restrict__ psum, const float* __restrict__ psq,
    float* __restrict__ colS, float* __restrict__ colQ) {
  const int wave = threadIdx.x >> 6, lane = threadIdx.x & 63;  // wave 0..15
  const int c = blockIdx.x * 64 + lane;  // 0..1023
  float s = 0.f, q = 0.f;
#pragma unroll 8
  for (int ch = wave; ch < NCHUNK; ch += 16) {
    s += psum[ch * DTOT + c];
    q += psq[ch * DTOT + c];
  }
  __shared__ float ls[16][64], lq[16][64];
  ls[wave][lane] = s;
  lq[wave][lane] = q;
  __syncthreads();
  if (threadIdx.x < 64) {
    float S = 0.f, Q = 0.f;
#pragma unroll
    for (int k = 0; k < 16; ++k) {
      S += ls[k][lane];
      Q += lq[k][lane];
    }
    colS[c] = S;
    colQ[c] = Q;
  }
}

// ---------------------------------------------------------------------------
// K3: fused feat + GEMV, zero LDS. grid = 1024 blocks x 256 thr (4 waves);
// each wave handles 4 consecutive rows. Each lane's 16 columns
// (d = k*128 + lane*2, k=0..7) are fixed across rows -> preload all per-column
// constants (2gS, -gQ, w0, w1) into 64 registers with coalesced float2 loads,
// then the row loop is: 8 float2 global loads + FMA/exp only.
// ---------------------------------------------------------------------------
__global__ __launch_bounds__(256) void svm_logits(
    const float* __restrict__ ts, const float* __restrict__ m0,
    const float* __restrict__ m1, const float* __restrict__ w,
    const float* __restrict__ b, const float* __restrict__ colS,
    const float* __restrict__ colQ, float* __restrict__ out) {
  const int tid = threadIdx.x;
  const int wave = tid >> 6, lane = tid & 63;
  const float b0 = b[0], b1 = b[1];           // uniform -> scalar loads
  const float c2 = -GAMMA_F * (float)NROWS;   // -gamma*N

  // Per-lane register constants for its 16 fixed columns.
  float c1a[8], c1b[8], c0a[8], c0b[8];
  float w0a[8], w0b[8], w1a[8], w1b[8];
#pragma unroll
  for (int k = 0; k < 8; ++k) {
    const int d = k * 128 + lane * 2;         // even, 0..1022
    float2 cs = *reinterpret_cast<const float2*>(colS + d);
    float2 cq = *reinterpret_cast<const float2*>(colQ + d);
    float2 v0 = *reinterpret_cast<const float2*>(w + d);
    float2 v1 = *reinterpret_cast<const float2*>(w + DTOT + d);
    c1a[k] = 2.0f * GAMMA_F * cs.x;
    c1b[k] = 2.0f * GAMMA_F * cs.y;
    c0a[k] = -GAMMA_F * cq.x;
    c0b[k] = -GAMMA_F * cq.y;
    w0a[k] = v0.x; w0b[k] = v0.y;
    w1a[k] = v1.x; w1b[k] = v1.y;
  }

  const int gw = blockIdx.x * 4 + wave;       // 0..4095
#pragma unroll
  for (int rr = 0; rr < 4; ++rr) {
    const int i = gw * 4 + rr;                // row, < 16384
    const float* row = ts + (size_t)i * DTS;
    float acc0 = 0.f, acc1 = 0.f;
#pragma unroll
    for (int k = 0; k < 8; ++k) {
      const int d = k * 128 + lane * 2;       // even, 0..1022
      float x0, x1;
      if (d < DTS) {
        float2 v = *reinterpret_cast<const float2*>(row + d);
        x0 = v.x; x1 = v.y;
      } else {                                // d == 1022 -> meta columns
        x0 = m0[i]; x1 = m1[i];
      }
      const float p0 = (c2 * x0 + c1a[k]) * x0 + c0a[k];
      const float p1 = (c2 * x1 + c1b[k]) * x1 + c0b[k];
      const float f0 = __expf(p0);
      const float f1 = __expf(p1);
      acc0 += f0 * w0a[k] + f1 * w0b[k];
      acc1 += f0 * w1a[k] + f1 * w1b[k];
    }
#pragma unroll
    for (int off = 32; off; off >>= 1) {
      acc0 += __shfl_down(acc0, off);
      acc1 += __shfl_down(acc1, off);
    }
    if (lane == 0) {
      out[i * 2 + 0] = acc0 + b0;
      out[i * 2 + 1] = acc1 + b1;
    }
  }
}

extern "C" void kernel_launch(void* const* d_in, const int* in_sizes, int n_in,
                              void* d_out, int out_size, void* d_ws,
                              size_t ws_size, hipStream_t stream) {
  const float* ts = (const float*)d_in[0];   // [16384, 1022]
  const float* m0 = (const float*)d_in[1];   // [16384]
  const float* m1 = (const float*)d_in[2];   // [16384]
  const float* w  = (const float*)d_in[3];   // [2, 1024]
  const float* b  = (const float*)d_in[4];   // [2]
  float* out = (float*)d_out;                // [16384, 2]

  float* psum = (float*)d_ws;                // [NCHUNK][1024]
  float* psq  = psum + NCHUNK * DTOT;        // [NCHUNK][1024]
  float* colS = psq + NCHUNK * DTOT;         // [1024]
  float* colQ = colS + DTOT;                 // [1024]

  colsum_partial<<<dim3(2, NCHUNK), 256, 0, stream>>>(ts, m0, m1, psum, psq);
  colsum_final<<<dim3(16), 1024, 0, stream>>>(psum, psq, colS, colQ);
  svm_logits<<<dim3(1024), 256, 0, stream>>>(ts, m0, m1, w, b, colS, colQ,
                                             out);
}